// Round 14
// baseline (401.241 us; speedup 1.0000x reference)
//
#include <hip/hip_runtime.h>
#include <stdint.h>

#define B_ROWS 8192
#define I_DIM  1024
#define N_DIM  1024
#define NDEG   9                  // D+1 (d = 0..8)
#define K_DIM  (I_DIM * (NDEG-1)) // 8192; k = i*8 + (d-1), d = 1..8 (d=0 folded into bias)

#define BM 256
#define BN 128
#define BK 64
#define NT (K_DIM / BK)           // 128 K-tiles; tile kt covers i in [kt*8, kt*8+8)

typedef __attribute__((ext_vector_type(8)))  short short8;
typedef __attribute__((ext_vector_type(16))) float f32x16;

__device__ __forceinline__ unsigned short f2bf(float f) {
  union { float f; uint32_t u; } v; v.f = f;
  uint32_t u = v.u;
  u += 0x7FFFu + ((u >> 16) & 1u);   // round-to-nearest-even
  return (unsigned short)(u >> 16);
}

__device__ __forceinline__ float bf2f(unsigned short h) {
  union { uint32_t u; float f; } v; v.u = ((uint32_t)h) << 16;
  return v.f;
}

// packed f32->bf16 (RTNE), 1 instr for 2 values; no builtin on gfx950, asm only
__device__ __forceinline__ uint32_t pk_bf16(float lo, float hi) {
  uint32_t r;
  asm("v_cvt_pk_bf16_f32 %0, %1, %2" : "=v"(r) : "v"(lo), "v"(hi));
  return r;
}

// fast tanh: 1 - 2/(e^{2x}+1); exact limits at +-inf, err ~1e-7 << bf16 quantization
__device__ __forceinline__ float fast_tanh(float x) {
  float e = __expf(2.0f * x);
  return 1.0f - __fdividef(2.0f, e + 1.0f);
}

// ---------------- repack (R12-proven, unchanged): C[i,o,d] fp32 -> Bt2 fragment image ----
// Bt2 layout (shorts): nt*1048576 + kt*8192 + ((gb*8 + c)*256 + r31*8) + (d-1)
//   (o = nt*128 + gb*32 + r31, i = kt*8 + c) — the exact per-(nt,kt) fragment image.
// bias[o] += sum_i C[i,o,0].
__global__ __launch_bounds__(256) void repack_kernel(const float* __restrict__ cf,
                                                     unsigned short* __restrict__ Bt2,
                                                     float* __restrict__ bias) {
  __shared__ unsigned short L[32][584];   // [i_local][o_local*9+d], padded
  const int i0  = blockIdx.x * 32;
  const int o0  = blockIdx.y * 64;
  const int tid = threadIdx.x;

  #pragma unroll
  for (int j = 0; j < 18; ++j) {               // 18*256 = 4608 float4 = 32*576 floats
    const int f4  = j * 256 + tid;
    const int il  = f4 / 144;
    const int odq = f4 % 144;
    const float4 v = *reinterpret_cast<const float4*>(
        cf + ((size_t)(i0 + il) * N_DIM + o0) * NDEG + (size_t)odq * 4);
    ushort4 w;
    w.x = f2bf(v.x); w.y = f2bf(v.y); w.z = f2bf(v.z); w.w = f2bf(v.w);
    *reinterpret_cast<ushort4*>(&L[il][odq * 4]) = w;
  }
  __syncthreads();

  // one (o, i-octet) per thread: 8 x uint4 (8 d-values each), fragment-major addressing
  const int o_rel = tid >> 2;     // 0..63
  const int ci    = tid & 3;      // 0..3
  const int o     = o0 + o_rel;
  const int ntb   = o >> 7;
  const int gb    = (o & 127) >> 5;
  const int r31   = o & 31;
  const int kti   = (i0 >> 3) + ci;
  const size_t base = (size_t)ntb * 1048576 + (size_t)kti * 8192 + (size_t)r31 * 8;
  #pragma unroll
  for (int p = 0; p < 8; ++p) {   // i = i0 + ci*8 + p -> chunk c = p
    const int il = ci * 8 + p;
    uint4 u;
    u.x = (uint32_t)L[il][o_rel*9 + 1] | ((uint32_t)L[il][o_rel*9 + 2] << 16);
    u.y = (uint32_t)L[il][o_rel*9 + 3] | ((uint32_t)L[il][o_rel*9 + 4] << 16);
    u.z = (uint32_t)L[il][o_rel*9 + 5] | ((uint32_t)L[il][o_rel*9 + 6] << 16);
    u.w = (uint32_t)L[il][o_rel*9 + 7] | ((uint32_t)L[il][o_rel*9 + 8] << 16);
    *reinterpret_cast<uint4*>(Bt2 + base + (size_t)(gb * 8 + p) * 256) = u;
  }
  if (tid < 64) {
    float s = 0.f;
    #pragma unroll
    for (int il = 0; il < 32; ++il) s += bf2f(L[il][tid * 9]);
    atomicAdd(&bias[o0 + tid], s);
  }
}

// ---------------- gemm: NO LDS, NO BARRIERS, NO tT. ------------------------------------
// C[m,n] = bias[n] + sum_k T(x)[m,k]*Bt[n,k]. One MFMA A-fragment (16 B) = T_1..T_8 of
// ONE scalar t = clamp(tanh(x[row][i])) — computed IN-REGISTER from a direct 4-byte x
// load (R13's tT intermediate removed: workspace back to R12's proven 16.78 MB, and the
// tanh+clamp+recurrence+pk_bf16 path is numerically IDENTICAL to R12's passing producer).
// B-frags load straight from the Bt2 fragment image as coalesced dwordx4 (L2-resident).
// x loads: 8 scalar/lane/tile — 32 lanes read 32 consecutive rows' 32B i-windows; L1
// absorbs the 8x sector reuse. VALU (~450 cy/CU-tile incl. tanh) fits under the MFMA
// shadow (1033 cy). Every wave runs its K-loop independently; register double-buffer
// (1 tile deep) hides L2 latency; compiler inserts precise per-register vmcnt waits.
__global__ __launch_bounds__(512) void gemm_kernel(const float* __restrict__ x,
                                                   const unsigned short* __restrict__ Bt2,
                                                   const float* __restrict__ bias,
                                                   float* __restrict__ C) {
  const int tid  = threadIdx.x;
  const int lane = tid & 63;
  const int wave = tid >> 6;        // 0..7
  const int l31  = lane & 31;
  const int half = lane >> 5;       // 0..1
  const int wm   = wave >> 1;       // 0..3
  const int wn   = wave & 1;        // 0..1

  // bijective XCD swizzle: 8 n-blocks of one m-tile share bid%8 -> same XCD L2 (x reuse)
  const int bid = blockIdx.x;
  const int mt  = (bid & 7) + 8 * (bid >> 6);
  const int nt  = (bid >> 3) & 7;
  const int m0  = mt * BM;
  const int n0  = nt * BN;

  // per-lane x base: row = m0 + wm*64 + mi*32 + l31, i = kt*8 + ks*2 + half
  const float* xb = x + (size_t)(m0 + wm * 64 + l31) * I_DIM + half;
  // B frag = 16B at bf + kt*8192 + (ni*8 + ks*2)*256   (shorts)
  const unsigned short* bf = Bt2 + (size_t)nt * 1048576 + (size_t)(wn * 16 + half) * 256 + l31 * 8;

  f32x16 acc[2][2];
  #pragma unroll
  for (int a = 0; a < 2; ++a)
    #pragma unroll
    for (int b = 0; b < 2; ++b)
      #pragma unroll
      for (int r = 0; r < 16; ++r)
        acc[a][b][r] = 0.f;

#define LOADT(TS, kt_) {                                                                     \
    _Pragma("unroll")                                                                        \
    for (int mi = 0; mi < 2; ++mi)                                                           \
      _Pragma("unroll")                                                                      \
      for (int ks = 0; ks < 4; ++ks)                                                         \
        TS[mi][ks] = xb[(size_t)mi * 32 * I_DIM + (kt_) * 8 + ks * 2]; }

#define LOADB(BV, kt_) {                                                                     \
    _Pragma("unroll")                                                                        \
    for (int ni = 0; ni < 2; ++ni)                                                           \
      _Pragma("unroll")                                                                      \
      for (int ks = 0; ks < 4; ++ks)                                                         \
        BV[ni][ks] = *reinterpret_cast<const short8*>(                                       \
            bf + (size_t)(kt_) * 8192 + (ni * 8 + ks * 2) * 256); }

// in-register basis from RAW x: t = clamp(fast_tanh(xv)), then T_1..T_8 packed (== R12)
#define BASIS(AV, TS) {                                                                      \
    _Pragma("unroll")                                                                        \
    for (int mi = 0; mi < 2; ++mi)                                                           \
      _Pragma("unroll")                                                                      \
      for (int ks = 0; ks < 4; ++ks) {                                                       \
        float t = fast_tanh(TS[mi][ks]);                                                     \
        t = fminf(fmaxf(t, -0.999f), 0.999f);                                                \
        const float t2 = t + t;                                                              \
        const float T1 = t;                                                                  \
        const float T2 = t2 * t - 1.0f;                                                      \
        const float T3 = t2 * T2 - T1;                                                       \
        const float T4 = t2 * T3 - T2;                                                       \
        const float T5 = t2 * T4 - T3;                                                       \
        const float T6 = t2 * T5 - T4;                                                       \
        const float T7 = t2 * T6 - T5;                                                       \
        const float T8 = t2 * T7 - T6;                                                       \
        union { uint4 u; short8 s; } p;                                                      \
        p.u.x = pk_bf16(T1, T2); p.u.y = pk_bf16(T3, T4);                                    \
        p.u.z = pk_bf16(T5, T6); p.u.w = pk_bf16(T7, T8);                                    \
        AV[mi][ks] = p.s; } }

#define MFMA16(AV, BV) {                                                                     \
    _Pragma("unroll")                                                                        \
    for (int ks = 0; ks < 4; ++ks) {                                                         \
      acc[0][0] = __builtin_amdgcn_mfma_f32_32x32x16_bf16(AV[0][ks], BV[0][ks], acc[0][0], 0, 0, 0); \
      acc[0][1] = __builtin_amdgcn_mfma_f32_32x32x16_bf16(AV[0][ks], BV[1][ks], acc[0][1], 0, 0, 0); \
      acc[1][0] = __builtin_amdgcn_mfma_f32_32x32x16_bf16(AV[1][ks], BV[0][ks], acc[1][0], 0, 0, 0); \
      acc[1][1] = __builtin_amdgcn_mfma_f32_32x32x16_bf16(AV[1][ks], BV[1][ks], acc[1][1], 0, 0, 0); } }

  float  tsA[2][4], tsB[2][4];
  short8 bvA[2][4], bvB[2][4], av[2][4];

  LOADT(tsA, 0) LOADB(bvA, 0)
  for (int kt = 0; kt < 126; kt += 2) {
    LOADT(tsB, kt + 1) LOADB(bvB, kt + 1)   // prefetch kt+1 (consumed next half)
    BASIS(av, tsA)
    MFMA16(av, bvA)
    LOADT(tsA, kt + 2) LOADB(bvA, kt + 2)   // prefetch kt+2
    BASIS(av, tsB)
    MFMA16(av, bvB)
  }
  LOADT(tsB, 127) LOADB(bvB, 127)
  BASIS(av, tsA) MFMA16(av, bvA)            // tile 126
  BASIS(av, tsB) MFMA16(av, bvB)            // tile 127
#undef MFMA16
#undef BASIS
#undef LOADB
#undef LOADT

  // epilogue: 32x32 C/D layout col = lane&31, row = (reg&3) + 8*(reg>>2) + 4*(lane>>5)
  #pragma unroll
  for (int ni = 0; ni < 2; ++ni) {
    const int col  = n0 + wn * 64 + ni * 32 + l31;
    const float bc = bias[col];
    #pragma unroll
    for (int mi = 0; mi < 2; ++mi) {
      const int rbase = m0 + wm * 64 + mi * 32 + 4 * half;
      #pragma unroll
      for (int r = 0; r < 16; ++r) {
        const int row = rbase + (r & 3) + 8 * (r >> 2);
        C[(size_t)row * N_DIM + col] = acc[mi][ni][r] + bc;
      }
    }
  }
}

extern "C" void kernel_launch(void* const* d_in, const int* in_sizes, int n_in,
                              void* d_out, int out_size, void* d_ws, size_t ws_size,
                              hipStream_t stream) {
  const float* x      = (const float*)d_in[0];
  const float* coeffs = (const float*)d_in[1];
  float* y            = (float*)d_out;

  const size_t bt_bytes = (size_t)N_DIM * K_DIM * sizeof(unsigned short); // 16.78 MB
  unsigned short* Bt2 = (unsigned short*)d_ws;
  float* bias         = (float*)((char*)d_ws + bt_bytes);

  // bias accumulator must start at zero (ws is poisoned 0xAA each call)
  hipMemsetAsync(bias, 0, N_DIM * sizeof(float), stream);

  repack_kernel<<<dim3(I_DIM / 32, N_DIM / 64), 256, 0, stream>>>(coeffs, Bt2, bias);

  // LDS-free, barrier-free gemm: 256 blocks (1/CU), 512 threads
  gemm_kernel<<<(B_ROWS / BM) * (N_DIM / BN), 512, 0, stream>>>(x, Bt2, bias, y);
}